// Round 12
// baseline (404.167 us; speedup 1.0000x reference)
//
#include <hip/hip_runtime.h>
#include <math.h>

// Problem constants (from setup_inputs)
constexpr int B   = 4;
constexpr int N   = 8192;
constexpr int M   = 2048;
constexpr int C1  = 128;
constexpr int C2  = 256;
constexpr int HCH = 256;   // H
constexpr int CIN = 384;   // C2 + C1
constexpr float BN_EPS = 1e-5f;
constexpr float SLOPE  = 0.2f;
constexpr float BN_CNT = (float)(B * N);   // BN reduces over (B, N)

typedef __attribute__((ext_vector_type(8))) short short8;   // 8 bf16 (4 VGPR)
typedef __attribute__((ext_vector_type(4))) float f32x4;    // MFMA C/D

// f32 -> bf16 round-to-nearest-even
__device__ __forceinline__ unsigned short bfh(float x) {
  unsigned int u = __float_as_uint(x);
  return (unsigned short)((u + 0x7fffu + ((u >> 16) & 1u)) >> 16);
}
__device__ __forceinline__ float bf2f(unsigned short h) {
  return __uint_as_float((unsigned int)h << 16);
}
__device__ __forceinline__ unsigned int pk(unsigned short a, unsigned short b) {
  return (unsigned int)a | ((unsigned int)b << 16);
}

// ---------------- zero stats ----------------
__global__ void k_zero(float* __restrict__ stats) {
  int i = blockIdx.x * blockDim.x + threadIdx.x;
  if (i < 1024) stats[i] = 0.f;
}

// ---------------- three_nn + inverse-distance weights ----------------
__global__ __launch_bounds__(256) void k_nn(const float* __restrict__ xyz1,
                                            const float* __restrict__ xyz2,
                                            float* __restrict__ wgt,
                                            int* __restrict__ idxo) {
  __shared__ float4 q[4][512];
  __shared__ float  md[4][64][3];
  __shared__ int    mi[4][64][3];
  const int tid = threadIdx.x;
  const int b   = blockIdx.y;
  const int n0  = blockIdx.x * 64;

  const float* src = xyz2 + (size_t)b * M * 3;
  for (int i = tid; i < M; i += 256) {
    float x = src[i*3+0], y = src[i*3+1], z = src[i*3+2];
    q[i >> 9][i & 511] = make_float4(x, y, z, x*x + y*y + z*z);
  }
  __syncthreads();

  const int w = tid >> 6;
  const int t = tid & 63;
  const int n = n0 + t;
  const float* p = xyz1 + ((size_t)b * N + n) * 3;
  const float px = p[0], py = p[1], pz = p[2];
  const float n1 = px*px + py*py + pz*pz;

  float d0 = 3.4e38f, d1 = 3.4e38f, d2 = 3.4e38f;
  int   j0 = 0, j1 = 0, j2 = 0;
  const float4* qs = q[w];
  #pragma unroll 4
  for (int r = 0; r < 512; ++r) {
    float4 c = qs[r];
    float dot = px*c.x + py*c.y + pz*c.z;
    float d = fmaf(-2.f, dot, n1 + c.w);
    if (d < d2) {
      int m = (w << 9) + r;
      if (d < d1) {
        if (d < d0) { d2 = d1; j2 = j1; d1 = d0; j1 = j0; d0 = d; j0 = m; }
        else        { d2 = d1; j2 = j1; d1 = d;  j1 = m; }
      } else        { d2 = d;  j2 = m; }
    }
  }
  md[w][t][0] = d0; md[w][t][1] = d1; md[w][t][2] = d2;
  mi[w][t][0] = j0; mi[w][t][1] = j1; mi[w][t][2] = j2;
  __syncthreads();

  if (tid < 64) {
    float e0 = 3.4e38f, e1 = 3.4e38f, e2 = 3.4e38f;
    int   i0 = 0, i1 = 0, i2 = 0;
    #pragma unroll
    for (int s = 0; s < 4; ++s) {
      #pragma unroll
      for (int k = 0; k < 3; ++k) {
        float d = md[s][tid][k];
        int   m = mi[s][tid][k];
        if (d < e2) {
          if (d < e1) {
            if (d < e0) { e2 = e1; i2 = i1; e1 = e0; i1 = i0; e0 = d; i0 = m; }
            else        { e2 = e1; i2 = i1; e1 = d;  i1 = m; }
          } else        { e2 = d;  i2 = m; }
        }
      }
    }
    e0 = fmaxf(e0, 1e-10f); e1 = fmaxf(e1, 1e-10f); e2 = fmaxf(e2, 1e-10f);
    float r0 = 1.f / e0, r1 = 1.f / e1, r2 = 1.f / e2;
    float s  = r0 + r1 + r2;
    size_t base = ((size_t)b * N + n0 + tid) * 3;
    wgt[base+0] = r0 / s;  wgt[base+1] = r1 / s;  wgt[base+2] = r2 / s;
    idxo[base+0] = i0;     idxo[base+1] = i1;     idxo[base+2] = i2;
  }
}

// ---------------- transpose points2: (B,C2,M) -> (B,M,C2) ----------------
__global__ __launch_bounds__(256) void k_tr(const float* __restrict__ P2,
                                            float* __restrict__ P2T) {
  __shared__ float t[32][33];
  const int b  = blockIdx.z;
  const int m0 = blockIdx.x * 32;
  const int c0 = blockIdx.y * 32;
  const int tx = threadIdx.x & 31;
  const int ty = threadIdx.x >> 5;
  const float* src = P2 + (size_t)b * C2 * M;
  #pragma unroll
  for (int j = 0; j < 4; ++j)
    t[ty + j*8][tx] = src[(size_t)(c0 + ty + j*8) * M + m0 + tx];
  __syncthreads();
  float* dst = P2T + (size_t)b * M * C2;
  #pragma unroll
  for (int j = 0; j < 4; ++j)
    dst[(size_t)(m0 + ty + j*8) * C2 + c0 + tx] = t[tx][ty + j*8];
}

// ---------------- interp + concat, emit hi/lo bf16 in [n][k] layout ----------------
// XhT/XlT: [b][n][CIN] bf16. 4 channel-quarters per n handled by 4 lane-groups
// (4x the thread parallelism of the old version -> better gather-latency hiding).
__global__ __launch_bounds__(256) void k_interp(const float* __restrict__ P2T,
                                                const float* __restrict__ points1,
                                                const float* __restrict__ wgt,
                                                const int* __restrict__ idx,
                                                unsigned short* __restrict__ Xh,
                                                unsigned short* __restrict__ Xl) {
  const int tid = threadIdx.x;
  const int q   = tid >> 6;                 // channel quarter 0..3
  const int b   = blockIdx.y;
  const int n   = blockIdx.x * 64 + (tid & 63);
  const size_t base = (size_t)b * N + n;
  const int i0 = idx[base*3+0], i1 = idx[base*3+1], i2 = idx[base*3+2];
  const float w0 = wgt[base*3+0], w1 = wgt[base*3+1], w2 = wgt[base*3+2];
  const float4* r0 = (const float4*)(P2T + ((size_t)b * M + i0) * C2) + q*16;
  const float4* r1 = (const float4*)(P2T + ((size_t)b * M + i1) * C2) + q*16;
  const float4* r2 = (const float4*)(P2T + ((size_t)b * M + i2) * C2) + q*16;
  unsigned short* rh = Xh + base * CIN;
  unsigned short* rl = Xl + base * CIN;

  // interp channels q*64 .. q*64+63
  #pragma unroll 4
  for (int c4 = 0; c4 < 16; ++c4) {
    float4 a0 = r0[c4], a1 = r1[c4], a2 = r2[c4];
    float v0 = w0*a0.x + w1*a1.x + w2*a2.x;
    float v1 = w0*a0.y + w1*a1.y + w2*a2.y;
    float v2 = w0*a0.z + w1*a1.z + w2*a2.z;
    float v3 = w0*a0.w + w1*a1.w + w2*a2.w;
    unsigned short h0=bfh(v0), h1=bfh(v1), h2=bfh(v2), h3=bfh(v3);
    uint2 sh; sh.x = pk(h0,h1); sh.y = pk(h2,h3);
    uint2 sl; sl.x = pk(bfh(v0-bf2f(h0)), bfh(v1-bf2f(h1)));
              sl.y = pk(bfh(v2-bf2f(h2)), bfh(v3-bf2f(h3)));
    *(uint2*)&rh[q*64 + c4*4] = sh;
    *(uint2*)&rl[q*64 + c4*4] = sl;
  }
  // points1 channels q*32 .. q*32+31 -> slots 256+...
  const float* p1 = points1 + ((size_t)b * C1 + q*32) * N + n;
  #pragma unroll 4
  for (int j = 0; j < 32; j += 4) {
    float v0 = p1[(size_t)(j+0) * N];
    float v1 = p1[(size_t)(j+1) * N];
    float v2 = p1[(size_t)(j+2) * N];
    float v3 = p1[(size_t)(j+3) * N];
    unsigned short h0=bfh(v0), h1=bfh(v1), h2=bfh(v2), h3=bfh(v3);
    uint2 sh; sh.x = pk(h0,h1); sh.y = pk(h2,h3);
    uint2 sl; sl.x = pk(bfh(v0-bf2f(h0)), bfh(v1-bf2f(h1)));
              sl.y = pk(bfh(v2-bf2f(h2)), bfh(v3-bf2f(h3)));
    *(uint2*)&rh[256 + q*32 + j] = sh;
    *(uint2*)&rl[256 + q*32 + j] = sl;
  }
}

// ---------------- split f32 -> bf16 hi/lo (for W1, W2) ----------------
__global__ void k_split(const float* __restrict__ src,
                        unsigned short* __restrict__ h,
                        unsigned short* __restrict__ l, int n) {
  int i = blockIdx.x * 256 + threadIdx.x;
  if (i < n) {
    float v = src[i];
    unsigned short hh = bfh(v);
    h[i] = hh;
    l[i] = bfh(v - bf2f(hh));
  }
}

// ---------------- mid: BN1 affine + LeakyReLU + split + transpose ----------------
// Y1 f32 [b][o][n] -> Th/Tl bf16 [b][n][HCH]
__global__ __launch_bounds__(256) void k_mid(const float* __restrict__ Y1,
                                             const float* __restrict__ coef,
                                             unsigned short* __restrict__ Th,
                                             unsigned short* __restrict__ Tl) {
  __shared__ float T[32][33];
  const int b  = blockIdx.z;
  const int n0 = blockIdx.x * 32;
  const int o0 = blockIdx.y * 32;
  const int tx = threadIdx.x & 31;
  const int ty = threadIdx.x >> 5;
  #pragma unroll
  for (int j = 0; j < 4; ++j) {
    const int o = o0 + ty + j*8;
    const float a = coef[o], bb = coef[256 + o];
    float t = fmaf(a, Y1[((size_t)b * HCH + o) * N + n0 + tx], bb);
    T[ty + j*8][tx] = t >= 0.f ? t : SLOPE * t;
  }
  __syncthreads();
  const int r = threadIdx.x >> 3;   // n-within 0..31
  const int u = threadIdx.x & 7;    // u32-pair base
  const size_t ro = ((size_t)b * N + n0 + r) * HCH + o0;
  #pragma unroll
  for (int uu = u; uu < 16; uu += 8) {
    float v0 = T[uu*2][r], v1 = T[uu*2+1][r];
    unsigned short h0 = bfh(v0), h1 = bfh(v1);
    ((unsigned int*)&Th[ro])[uu] = pk(h0, h1);
    ((unsigned int*)&Tl[ro])[uu] = pk(bfh(v0 - bf2f(h0)), bfh(v1 - bf2f(h1)));
  }
}

// ---------------- bf16x3 MFMA GEMM, pre-split operands ----------------
// Y(B,HCH,N) = W(HCH,K) @ X(B,K,N) + bias, operands given as bf16 hi/lo:
// Wh/Wl [o][K], Xh/Xl [b][n][K] (k-contiguous!). Tile 64(o) x 128(n), BK=32,
// 4 waves 2x2, wave = 32o x 64n = 2x4 16x16x32 fragments. Staging = pure 16B
// vector loads (no conversion, no transpose). 1024 blocks -> 4 blocks/CU.
template <int K>
__global__ __launch_bounds__(256, 4) void k_gemm(const unsigned short* __restrict__ Wh,
                                                 const unsigned short* __restrict__ Wl,
                                                 const float* __restrict__ bias,
                                                 const unsigned short* __restrict__ Xh,
                                                 const unsigned short* __restrict__ Xl,
                                                 float* __restrict__ Yout,
                                                 float* __restrict__ stats) {
  constexpr int RL = 40;  // padded row (bf16) -> <=2-way LDS bank alias (free)
  __shared__ unsigned short Whs[64*RL], Wls[64*RL], Xhs[128*RL], Xls[128*RL];  // 30 KB

  const int tid = threadIdx.x;
  const int n0 = blockIdx.x * 128;
  const int o0 = blockIdx.y * 64;
  const int b  = blockIdx.z;

  const int srw = tid >> 2, kq = (tid & 3) * 8;   // W stage: 4 threads/row
  const int srx = tid >> 1, kh = (tid & 1) * 16;  // X stage: 2 threads/row

  const unsigned short* WhP = Wh + (size_t)(o0 + srw) * K;
  const unsigned short* WlP = Wl + (size_t)(o0 + srw) * K;
  const unsigned short* XhP = Xh + ((size_t)b * N + n0 + srx) * K;
  const unsigned short* XlP = Xl + ((size_t)b * N + n0 + srx) * K;

  const int lane = tid & 63;
  const int wv = tid >> 6;
  const int wm = wv >> 1, wn = wv & 1;
  const int lr = lane & 15;
  const int lk = (lane >> 4) * 8;

  f32x4 acc[2][4] = {};

  for (int k0 = 0; k0 < K; k0 += 32) {
    *(uint4*)&Whs[srw*RL + kq]     = *(const uint4*)&WhP[k0 + kq];
    *(uint4*)&Wls[srw*RL + kq]     = *(const uint4*)&WlP[k0 + kq];
    *(uint4*)&Xhs[srx*RL + kh]     = *(const uint4*)&XhP[k0 + kh];
    *(uint4*)&Xhs[srx*RL + kh + 8] = *(const uint4*)&XhP[k0 + kh + 8];
    *(uint4*)&Xls[srx*RL + kh]     = *(const uint4*)&XlP[k0 + kh];
    *(uint4*)&Xls[srx*RL + kh + 8] = *(const uint4*)&XlP[k0 + kh + 8];
    __syncthreads();

    short8 bh[4], bl[4], ah[2], al[2];
    #pragma unroll
    for (int n = 0; n < 4; ++n) {
      bh[n] = *(const short8*)&Xhs[(wn*64 + n*16 + lr)*RL + lk];
      bl[n] = *(const short8*)&Xls[(wn*64 + n*16 + lr)*RL + lk];
    }
    #pragma unroll
    for (int m = 0; m < 2; ++m) {
      ah[m] = *(const short8*)&Whs[(wm*32 + m*16 + lr)*RL + lk];
      al[m] = *(const short8*)&Wls[(wm*32 + m*16 + lr)*RL + lk];
    }
    #pragma unroll
    for (int m = 0; m < 2; ++m) {
      #pragma unroll
      for (int n = 0; n < 4; ++n) {
        acc[m][n] = __builtin_amdgcn_mfma_f32_16x16x32_bf16(ah[m], bh[n], acc[m][n], 0, 0, 0);
        acc[m][n] = __builtin_amdgcn_mfma_f32_16x16x32_bf16(ah[m], bl[n], acc[m][n], 0, 0, 0);
        acc[m][n] = __builtin_amdgcn_mfma_f32_16x16x32_bf16(al[m], bh[n], acc[m][n], 0, 0, 0);
      }
    }
    __syncthreads();
  }

  // epilogue: bias, store Y f32, per-channel stats (C layout m89: row=(lane>>4)*4+r, col=lr)
  #pragma unroll
  for (int m = 0; m < 2; ++m) {
    #pragma unroll
    for (int r = 0; r < 4; ++r) {
      const int o = o0 + wm*32 + m*16 + (lane >> 4)*4 + r;
      const float bi = bias[o];
      float s = 0.f, qq = 0.f;
      #pragma unroll
      for (int n = 0; n < 4; ++n) {
        float v = acc[m][n][r] + bi;
        Yout[((size_t)b * HCH + o) * N + n0 + wn*64 + n*16 + lr] = v;
        s += v; qq += v*v;
      }
      #pragma unroll
      for (int off = 1; off < 16; off <<= 1) {
        s  += __shfl_xor(s, off);
        qq += __shfl_xor(qq, off);
      }
      if (lr == 0) {
        atomicAdd(&stats[o], s);
        atomicAdd(&stats[256 + o], qq);
      }
    }
  }
}

// ---------------- BN finalize ----------------
__global__ void k_fin(const float* __restrict__ stats,
                      const float* __restrict__ gamma,
                      const float* __restrict__ beta,
                      float* __restrict__ coef) {
  const int c = threadIdx.x;
  const float mean = stats[c] / BN_CNT;
  const float var  = stats[256 + c] / BN_CNT - mean * mean;
  const float a    = gamma[c] / sqrtf(var + BN_EPS);
  coef[c]       = a;
  coef[256 + c] = fmaf(-a, mean, beta[c]);
}

// ---------------- final BN apply + LeakyReLU -> out ----------------
__global__ __launch_bounds__(256) void k_apply(const float* __restrict__ Y,
                                               const float* __restrict__ coef,
                                               float* __restrict__ out) {
  const size_t total = (size_t)B * HCH * N / 4;
  const float4* y4 = (const float4*)Y;
  float4* o4 = (float4*)out;
  for (size_t f = (size_t)blockIdx.x * blockDim.x + threadIdx.x; f < total;
       f += (size_t)gridDim.x * blockDim.x) {
    const int c = (int)((f / (N / 4)) % HCH);
    const float a = coef[c], bb = coef[256 + c];
    float4 v = y4[f];
    float t;
    t = fmaf(a, v.x, bb); v.x = t >= 0.f ? t : SLOPE * t;
    t = fmaf(a, v.y, bb); v.y = t >= 0.f ? t : SLOPE * t;
    t = fmaf(a, v.z, bb); v.z = t >= 0.f ? t : SLOPE * t;
    t = fmaf(a, v.w, bb); v.w = t >= 0.f ? t : SLOPE * t;
    o4[f] = v;
  }
}

extern "C" void kernel_launch(void* const* d_in, const int* in_sizes, int n_in,
                              void* d_out, int out_size, void* d_ws, size_t ws_size,
                              hipStream_t stream) {
  const float* xyz1    = (const float*)d_in[0];
  const float* xyz2    = (const float*)d_in[1];
  const float* points1 = (const float*)d_in[2];
  const float* points2 = (const float*)d_in[3];
  const float* W1      = (const float*)d_in[4];
  const float* b1      = (const float*)d_in[5];
  const float* gamma1  = (const float*)d_in[6];
  const float* beta1   = (const float*)d_in[7];
  const float* W2      = (const float*)d_in[8];
  const float* b2      = (const float*)d_in[9];
  const float* gamma2  = (const float*)d_in[10];
  const float* beta2   = (const float*)d_in[11];

  // workspace layout (bytes); aliases: Y2<-Y1, Y1hT<-XhT, Y1lT<-XlT
  char* w = (char*)d_ws;
  float* wgt            = (float*)w;                         w += (size_t)B*N*3*4;      // 384 KB
  int*   idx            = (int*)w;                           w += (size_t)B*N*3*4;      // 384 KB
  float* P2T            = (float*)w;                         w += (size_t)B*M*C2*4;     // 8 MB
  float* Y1             = (float*)w;                         w += (size_t)B*HCH*N*4;    // 32 MB (Y2 alias)
  unsigned short* XhT   = (unsigned short*)w;                w += (size_t)B*N*CIN*2;    // 24 MB (Y1hT alias)
  unsigned short* XlT   = (unsigned short*)w;                w += (size_t)B*N*CIN*2;    // 24 MB (Y1lT alias)
  unsigned short* W1h   = (unsigned short*)w;                w += (size_t)HCH*CIN*2;
  unsigned short* W1l   = (unsigned short*)w;                w += (size_t)HCH*CIN*2;
  unsigned short* W2h   = (unsigned short*)w;                w += (size_t)HCH*HCH*2;
  unsigned short* W2l   = (unsigned short*)w;                w += (size_t)HCH*HCH*2;
  float* stats1         = (float*)w;                         w += 512*4;
  float* stats2         = (float*)w;                         w += 512*4;
  float* coef1          = (float*)w;                         w += 512*4;
  float* coef2          = (float*)w;                         w += 512*4;
  float* Y2             = Y1;
  unsigned short* Y1hT  = XhT;
  unsigned short* Y1lT  = XlT;

  k_zero<<<4, 256, 0, stream>>>(stats1);
  k_nn<<<dim3(N / 64, B), 256, 0, stream>>>(xyz1, xyz2, wgt, idx);
  k_tr<<<dim3(M / 32, C2 / 32, B), 256, 0, stream>>>(points2, P2T);
  k_interp<<<dim3(N / 64, B), 256, 0, stream>>>(P2T, points1, wgt, idx, XhT, XlT);
  k_split<<<(HCH*CIN + 255) / 256, 256, 0, stream>>>(W1, W1h, W1l, HCH*CIN);
  k_split<<<(HCH*HCH + 255) / 256, 256, 0, stream>>>(W2, W2h, W2l, HCH*HCH);
  k_gemm<CIN><<<dim3(N / 128, HCH / 64, B), 256, 0, stream>>>(W1h, W1l, b1, XhT, XlT, Y1, stats1);
  k_fin<<<1, 256, 0, stream>>>(stats1, gamma1, beta1, coef1);
  k_mid<<<dim3(N / 32, HCH / 32, B), 256, 0, stream>>>(Y1, coef1, Y1hT, Y1lT);
  k_gemm<HCH><<<dim3(N / 128, HCH / 64, B), 256, 0, stream>>>(W2h, W2l, b2, Y1hT, Y1lT, Y2, stats2);
  k_fin<<<1, 256, 0, stream>>>(stats2, gamma2, beta2, coef2);
  k_apply<<<2048, 256, 0, stream>>>(Y2, coef2, (float*)d_out);
}